// Round 8
// baseline (313.722 us; speedup 1.0000x reference)
//
#include <hip/hip_runtime.h>
#include <hip/hip_bf16.h>
#include <cmath>

#define BS   4
#define NQ   1000
#define CDIM 256
#define NH   8
#define HD   32
#define NVAL 20000
#define FFND 512
#define PN   4
#define WBEV 100
#define HBEV 200
#define TK   32

typedef __bf16 v8bf __attribute__((ext_vector_type(8)));
typedef float  v4f  __attribute__((ext_vector_type(4)));

__device__ __forceinline__ void gload_lds16(const void* g, void* l) {
    __builtin_amdgcn_global_load_lds(
        (const __attribute__((address_space(1))) unsigned int*)g,
        (__attribute__((address_space(3))) unsigned int*)l, 16, 0, 0);
}

// ============ prep_all: weight cast | prep | soaw pack ============
__global__ __launch_bounds__(256) void prep_all_kernel(
    const float* __restrict__ query, const float* __restrict__ qpos,
    const float* __restrict__ in_w, const float* __restrict__ mha_ow,
    const float* __restrict__ vp_w, const float* __restrict__ op_w,
    const float* __restrict__ ffn_w1, const float* __restrict__ ffn_w2,
    const float* __restrict__ so_w, const float* __restrict__ aw_w,
    const float* __restrict__ so_b, const float* __restrict__ aw_b,
    float* __restrict__ x, float* __restrict__ qpos_t,
    __bf16* __restrict__ x_bf, __bf16* __restrict__ xq_bf,
    __bf16* __restrict__ wb, __bf16* __restrict__ wsmall,
    float* __restrict__ bsmall)
{
    int blk = blockIdx.x, tid = threadIdx.x;
    if (blk < 640) {
        long e = ((long)blk * 256 + tid) * 4;
        const float* src; long off;
        if      (e < 196608) { src = in_w;   off = e; }
        else if (e < 262144) { src = mha_ow; off = e - 196608; }
        else if (e < 327680) { src = vp_w;   off = e - 262144; }
        else if (e < 393216) { src = op_w;   off = e - 327680; }
        else if (e < 524288) { src = ffn_w1; off = e - 393216; }
        else                 { src = ffn_w2; off = e - 524288; }
        float4 v = *(const float4*)(src + off);
        __bf16* d = wb + e;
        d[0] = (__bf16)v.x; d[1] = (__bf16)v.y; d[2] = (__bf16)v.z; d[3] = (__bf16)v.w;
    } else if (blk < 4640) {
        int qb = blk - 640;
        int q = qb / BS, b = qb % BS;
        float qv = query[(q * BS + b) * CDIM + tid];
        float pv = qpos [(q * BS + b) * CDIM + tid];
        int o = (b * NQ + q) * CDIM + tid;
        x[o] = qv; qpos_t[o] = pv;
        x_bf[o] = (__bf16)qv; xq_bf[o] = (__bf16)(qv + pv);
    } else if (blk < 4672) {
        long e = ((long)(blk - 4640) * 256 + tid) * 4;
        int row = (int)(e >> 8), col = (int)(e & 255);
        float4 v = {0.f, 0.f, 0.f, 0.f};
        if (row < 64)      v = *(const float4*)(so_w + row * 256 + col);
        else if (row < 96) v = *(const float4*)(aw_w + (row - 64) * 256 + col);
        __bf16* d = wsmall + e;
        d[0] = (__bf16)v.x; d[1] = (__bf16)v.y; d[2] = (__bf16)v.z; d[3] = (__bf16)v.w;
    } else {
        if (tid < 128) bsmall[tid] = tid < 64 ? so_b[tid] : (tid < 96 ? aw_b[tid - 64] : 0.f);
    }
}

// ============ MFMA bf16 GEMM, BK=64 (used for soaw / ffn1) ============
template<int TBM, int TBN>
__global__ __launch_bounds__(256) void mgemm_kernel(
    const __bf16* __restrict__ A, const __bf16* __restrict__ W,
    const float* __restrict__ bias, float* __restrict__ Yf,
    __bf16* __restrict__ Yb, int M, int N, int K, int relu)
{
    constexpr int WMF = TBM / 32;
    constexpr int WNF = TBN / 32;
    __shared__ __bf16 As[TBM][64];
    __shared__ __bf16 Bs[TBN][64];
    int bm = blockIdx.y * TBM, bn = blockIdx.x * TBN;
    int tid = threadIdx.x;
    int wave = tid >> 6, lane = tid & 63, quad = lane >> 4, n16 = lane & 15;
    int wm = (wave & 1) * (TBM / 2), wn = (wave >> 1) * (TBN / 2);
    v4f acc[WMF][WNF] = {};

    for (int k0 = 0; k0 < K; k0 += 64) {
        __syncthreads();
        #pragma unroll
        for (int i = 0; i < TBM * 8 / 256; i++) {
            int e = i * 256 + tid;
            int r = e >> 3, c = (e & 7) ^ (r & 7);
            int row = bm + r; if (row > M - 1) row = M - 1;
            gload_lds16(A + (long)row * K + k0 + c * 8, &As[0][0] + e * 8);
        }
        #pragma unroll
        for (int i = 0; i < TBN * 8 / 256; i++) {
            int e = i * 256 + tid;
            int r = e >> 3, c = (e & 7) ^ (r & 7);
            gload_lds16(W + (long)(bn + r) * K + k0 + c * 8, &Bs[0][0] + e * 8);
        }
        __syncthreads();
        #pragma unroll
        for (int s = 0; s < 2; s++) {
            v8bf af[WMF], bfr[WNF];
            #pragma unroll
            for (int mi = 0; mi < WMF; mi++) {
                int row = wm + mi * 16 + n16;
                af[mi] = *(v8bf*)&As[row][(((quad + s * 4) ^ (row & 7))) * 8];
            }
            #pragma unroll
            for (int nj = 0; nj < WNF; nj++) {
                int row = wn + nj * 16 + n16;
                bfr[nj] = *(v8bf*)&Bs[row][(((quad + s * 4) ^ (row & 7))) * 8];
            }
            #pragma unroll
            for (int mi = 0; mi < WMF; mi++)
                #pragma unroll
                for (int nj = 0; nj < WNF; nj++)
                    acc[mi][nj] = __builtin_amdgcn_mfma_f32_16x16x32_bf16(af[mi], bfr[nj], acc[mi][nj], 0, 0, 0);
        }
    }

    #pragma unroll
    for (int mi = 0; mi < WMF; mi++) {
        #pragma unroll
        for (int r = 0; r < 4; r++) {
            int m = bm + wm + mi * 16 + quad * 4 + r;
            if (m >= M) continue;
            #pragma unroll
            for (int nj = 0; nj < WNF; nj++) {
                int nn = bn + wn + nj * 16 + n16;
                if (nn >= N) continue;
                float v = acc[mi][nj][r] + bias[nn];
                if (relu) v = fmaxf(v, 0.f);
                if (Yf) Yf[(long)m * N + nn] = v;
                if (Yb) Yb[(long)m * N + nn] = (__bf16)v;
            }
        }
    }
}

// ============ fused q|k|v projection: N=768, grid (12, 63) ============
__global__ __launch_bounds__(256) void qkv_kernel(
    const __bf16* __restrict__ xq, const __bf16* __restrict__ xv,
    const __bf16* __restrict__ W, const float* __restrict__ bias,
    __bf16* __restrict__ qk, __bf16* __restrict__ vh)
{
    __shared__ __bf16 As[64][64];
    __shared__ __bf16 Bs[64][64];
    int bm = blockIdx.y * 64, bn = blockIdx.x * 64;
    const __bf16* A = (bn < 512) ? xq : xv;
    int tid = threadIdx.x;
    int wave = tid >> 6, lane = tid & 63, quad = lane >> 4, n16 = lane & 15;
    int wm = (wave & 1) * 32, wn = (wave >> 1) * 32;
    v4f acc[2][2] = {};

    for (int k0 = 0; k0 < 256; k0 += 64) {
        __syncthreads();
        #pragma unroll
        for (int i = 0; i < 2; i++) {
            int e = i * 256 + tid;
            int r = e >> 3, c = (e & 7) ^ (r & 7);
            int row = bm + r; if (row > BS * NQ - 1) row = BS * NQ - 1;
            gload_lds16(A + (long)row * 256 + k0 + c * 8, &As[0][0] + e * 8);
        }
        #pragma unroll
        for (int i = 0; i < 2; i++) {
            int e = i * 256 + tid;
            int r = e >> 3, c = (e & 7) ^ (r & 7);
            gload_lds16(W + (long)(bn + r) * 256 + k0 + c * 8, &Bs[0][0] + e * 8);
        }
        __syncthreads();
        #pragma unroll
        for (int s = 0; s < 2; s++) {
            v8bf af[2], bfr[2];
            #pragma unroll
            for (int mi = 0; mi < 2; mi++) {
                int row = wm + mi * 16 + n16;
                af[mi] = *(v8bf*)&As[row][(((quad + s * 4) ^ (row & 7))) * 8];
            }
            #pragma unroll
            for (int nj = 0; nj < 2; nj++) {
                int row = wn + nj * 16 + n16;
                bfr[nj] = *(v8bf*)&Bs[row][(((quad + s * 4) ^ (row & 7))) * 8];
            }
            #pragma unroll
            for (int mi = 0; mi < 2; mi++)
                #pragma unroll
                for (int nj = 0; nj < 2; nj++)
                    acc[mi][nj] = __builtin_amdgcn_mfma_f32_16x16x32_bf16(af[mi], bfr[nj], acc[mi][nj], 0, 0, 0);
        }
    }

    #pragma unroll
    for (int mi = 0; mi < 2; mi++) {
        #pragma unroll
        for (int r = 0; r < 4; r++) {
            int m = bm + wm + mi * 16 + quad * 4 + r;
            if (m >= BS * NQ) continue;
            #pragma unroll
            for (int nj = 0; nj < 2; nj++) {
                int nn = bn + wn + nj * 16 + n16;
                float v = acc[mi][nj][r] + bias[nn];
                if (nn < 512) qk[(long)m * 512 + nn] = (__bf16)v;
                else          vh[(long)m * 256 + (nn - 512)] = (__bf16)v;
            }
        }
    }
}

// ============ GEMM + residual + LayerNorm epilogue (full-row blocks) ========
template<int KD, int MODE>
__global__ __launch_bounds__(256) void gemmln_kernel(
    const __bf16* __restrict__ A, const __bf16* __restrict__ W,
    const float* __restrict__ bias, const float* __restrict__ res,
    const float* __restrict__ g, const float* __restrict__ beta,
    const float* __restrict__ qpos_t,
    float* __restrict__ outf, __bf16* __restrict__ outb)
{
    __shared__ __bf16 As[16][64];
    __shared__ __bf16 Bs[256][64];
    __shared__ float redS[4][16], redQ[4][16];
    int bm = blockIdx.x * 16;
    int tid = threadIdx.x;
    int wave = tid >> 6, lane = tid & 63, quad = lane >> 4, n16 = lane & 15;
    int wn = wave * 64;
    v4f acc[4] = {};

    for (int k0 = 0; k0 < KD; k0 += 64) {
        __syncthreads();
        if (tid < 128) {
            int e = tid;
            int r = e >> 3, c = (e & 7) ^ (r & 7);
            gload_lds16(A + (long)(bm + r) * KD + k0 + c * 8, &As[0][0] + e * 8);
        }
        #pragma unroll
        for (int i = 0; i < 8; i++) {
            int e = i * 256 + tid;
            int r = e >> 3, c = (e & 7) ^ (r & 7);
            gload_lds16(W + (long)r * KD + k0 + c * 8, &Bs[0][0] + e * 8);
        }
        __syncthreads();
        #pragma unroll
        for (int s = 0; s < 2; s++) {
            v8bf af = *(v8bf*)&As[n16][(((quad + s * 4) ^ (n16 & 7))) * 8];
            #pragma unroll
            for (int nj = 0; nj < 4; nj++) {
                int row = wn + nj * 16 + n16;
                v8bf bfr = *(v8bf*)&Bs[row][(((quad + s * 4) ^ (row & 7))) * 8];
                acc[nj] = __builtin_amdgcn_mfma_f32_16x16x32_bf16(af, bfr, acc[nj], 0, 0, 0);
            }
        }
    }

    float y[4][4], s1[4] = {}, s2[4] = {};
    #pragma unroll
    for (int r = 0; r < 4; r++) {
        int m = bm + quad * 4 + r;
        #pragma unroll
        for (int nj = 0; nj < 4; nj++) {
            int nn = wn + nj * 16 + n16;
            float v = acc[nj][r] + bias[nn] + res[(long)m * 256 + nn];
            y[r][nj] = v;
            s1[r] += v; s2[r] += v * v;
        }
    }
    #pragma unroll
    for (int r = 0; r < 4; r++) {
        #pragma unroll
        for (int off = 1; off < 16; off <<= 1) {
            s1[r] += __shfl_xor(s1[r], off, 16);
            s2[r] += __shfl_xor(s2[r], off, 16);
        }
    }
    if (n16 == 0) {
        #pragma unroll
        for (int r = 0; r < 4; r++) {
            redS[wave][quad * 4 + r] = s1[r];
            redQ[wave][quad * 4 + r] = s2[r];
        }
    }
    __syncthreads();
    #pragma unroll
    for (int r = 0; r < 4; r++) {
        int mr = quad * 4 + r;
        float ts = redS[0][mr] + redS[1][mr] + redS[2][mr] + redS[3][mr];
        float tq = redQ[0][mr] + redQ[1][mr] + redQ[2][mr] + redQ[3][mr];
        float mean = ts * (1.0f / 256.0f);
        float var = tq * (1.0f / 256.0f) - mean * mean;
        float rinv = rsqrtf(var + 1e-5f);
        int m = bm + mr;
        #pragma unroll
        for (int nj = 0; nj < 4; nj++) {
            int nn = wn + nj * 16 + n16;
            float o = (y[r][nj] - mean) * rinv * g[nn] + beta[nn];
            if (MODE == 0) {
                outf[(long)m * 256 + nn] = o;
                outb[(long)m * 256 + nn] = (__bf16)(o + qpos_t[(long)m * 256 + nn]);
            } else if (MODE == 1) {
                outf[(long)m * 256 + nn] = o;
                outb[(long)m * 256 + nn] = (__bf16)o;
            } else {
                int b = m / NQ, q = m % NQ;
                outf[(long)(q * BS + b) * 256 + nn] = o;
            }
        }
    }
}

// ============ fused launch: flash-attn FIRST (0..511), then vgemm ============
// fattn blocks are the long serial chains -> dispatch them at t=0.
// vgemm: barrier-free, LDS-free: A/B MFMA fragments loaded straight from
// global (A fp32 + in-register cvt; B bf16 frag = 16B). No syncthreads ->
// no vmcnt(0) drain; compiler pipelines with fine-grained vmcnt(N).
__global__ __launch_bounds__(256) void fvg_kernel(
    const float* __restrict__ value, const __bf16* __restrict__ Wv,
    const float* __restrict__ bv, __bf16* __restrict__ vpj,
    const __bf16* __restrict__ qk, const __bf16* __restrict__ vh,
    __bf16* __restrict__ aout)
{
    __shared__ __align__(16) char smem[15360];
    int tid = threadIdx.x;
    int wave = tid >> 6, lane = tid & 63, quad = lane >> 4, n16 = lane & 15;

    if (blockIdx.x >= 512) {
        // ---------------- vgemm: TBM=64, TBN=256, barrier-free ----------------
        int bm = (blockIdx.x - 512) * 64;
        int wn = wave * 64;
        v4f acc[4][4] = {};
        #pragma unroll
        for (int k0 = 0; k0 < 256; k0 += 64) {
            #pragma unroll
            for (int s = 0; s < 2; s++) {
                int kc = k0 + s * 32 + quad * 8;
                v8bf af[4], bfr[4];
                #pragma unroll
                for (int mi = 0; mi < 4; mi++) {
                    const float* p = value + (long)(bm + mi * 16 + n16) * 256 + kc;
                    float4 a0 = *(const float4*)p;
                    float4 a1 = *(const float4*)(p + 4);
                    v8bf v;
                    v[0] = (__bf16)a0.x; v[1] = (__bf16)a0.y;
                    v[2] = (__bf16)a0.z; v[3] = (__bf16)a0.w;
                    v[4] = (__bf16)a1.x; v[5] = (__bf16)a1.y;
                    v[6] = (__bf16)a1.z; v[7] = (__bf16)a1.w;
                    af[mi] = v;
                }
                #pragma unroll
                for (int nj = 0; nj < 4; nj++)
                    bfr[nj] = *(const v8bf*)(Wv + (long)(wn + nj * 16 + n16) * 256 + kc);
                #pragma unroll
                for (int mi = 0; mi < 4; mi++)
                    #pragma unroll
                    for (int nj = 0; nj < 4; nj++)
                        acc[mi][nj] = __builtin_amdgcn_mfma_f32_16x16x32_bf16(af[mi], bfr[nj], acc[mi][nj], 0, 0, 0);
            }
        }
        #pragma unroll
        for (int mi = 0; mi < 4; mi++) {
            #pragma unroll
            for (int r = 0; r < 4; r++) {
                int m = bm + mi * 16 + quad * 4 + r;
                #pragma unroll
                for (int nj = 0; nj < 4; nj++) {
                    int nn = wn + nj * 16 + n16;
                    vpj[(long)m * 256 + nn] = (__bf16)(acc[mi][nj][r] + bv[nn]);
                }
            }
        }
    } else {
        // ---------------- fattn ----------------
        int fb = blockIdx.x;
        int qt = fb & 15, h = (fb >> 4) & 7, b = fb >> 7;
        __bf16* Ks = (__bf16*)smem;             // [2][TK][40]  5120 B
        __bf16* Vt = (__bf16*)(smem + 5120);    // [2][HD][40]  5120 B
        __bf16* Pl = (__bf16*)(smem + 10240);   // [4][16][40]  5120 B
        int n = n16;
        int q0 = qt * 64 + wave * 16;
        const float scale = 0.17677669529663687f;
        const float M0 = 8.0f;

        int qrow = q0 + n; if (qrow > NQ - 1) qrow = NQ - 1;
        v8bf aq = *(const v8bf*)(qk + (long)(b * NQ + qrow) * 512 + h * HD + quad * 8);

        v4f o0 = {}, o1 = {};
        float lp[4] = {0.f, 0.f, 0.f, 0.f};

        int sv = tid >> 7;
        int t2 = tid & 127;
        int key = t2 >> 2;
        int d8 = (t2 & 3) * 8;
        int vcol = key ^ (((d8 >> 3) & 1) << 4);

        auto loadtile = [&](int k0) -> v8bf {
            int krow = k0 + key; if (krow > NQ - 1) krow = NQ - 1;
            const __bf16* p = sv ? (vh + (long)(b * NQ + krow) * CDIM + h * HD + d8)
                                 : (qk + (long)(b * NQ + krow) * 512 + 256 + h * HD + d8);
            return *(const v8bf*)p;
        };

        v8bf stg = loadtile(0);
        int pb = 0;
        for (int k0 = 0; k0 < NQ; k0 += TK) {
            if (sv == 0) {
                *(v8bf*)&Ks[(pb * TK + key) * 40 + d8] = stg;
            } else {
                #pragma unroll
                for (int j = 0; j < 8; j++) Vt[(pb * HD + d8 + j) * 40 + vcol] = stg[j];
            }
            if (k0 + TK < NQ) stg = loadtile(k0 + TK);
            __syncthreads();

            v8bf bk0 = *(v8bf*)&Ks[(pb * TK + n) * 40 + quad * 8];
            v8bf bk1 = *(v8bf*)&Ks[(pb * TK + 16 + n) * 40 + quad * 8];
            v4f z = {};
            v4f S0 = __builtin_amdgcn_mfma_f32_16x16x32_bf16(aq, bk0, z, 0, 0, 0);
            v4f S1 = __builtin_amdgcn_mfma_f32_16x16x32_bf16(aq, bk1, z, 0, 0, 0);

            bool last = (k0 + TK > NQ);
            float p0[4], p1[4];
            #pragma unroll
            for (int r = 0; r < 4; r++) {
                p0[r] = __expf(fmaf(S0[r], scale, -M0));
                p1[r] = __expf(fmaf(S1[r], scale, -M0));
                if (last) {
                    if (k0 + n >= NQ)      p0[r] = 0.f;
                    if (k0 + 16 + n >= NQ) p1[r] = 0.f;
                }
                lp[r] += p0[r] + p1[r];
            }
            #pragma unroll
            for (int r = 0; r < 4; r++) {
                Pl[(wave * 16 + quad * 4 + r) * 40 + n]      = (__bf16)p0[r];
                Pl[(wave * 16 + quad * 4 + r) * 40 + 16 + n] = (__bf16)p1[r];
            }
            asm volatile("s_waitcnt lgkmcnt(0)" ::: "memory");
            v8bf ap = *(v8bf*)&Pl[(wave * 16 + n) * 40 + quad * 8];
            int vc = (quad * 8) ^ (((n >> 3) & 1) << 4);
            v8bf bv0 = *(v8bf*)&Vt[(pb * HD + n) * 40 + vc];
            v8bf bv1 = *(v8bf*)&Vt[(pb * HD + 16 + n) * 40 + vc];
            o0 = __builtin_amdgcn_mfma_f32_16x16x32_bf16(ap, bv0, o0, 0, 0, 0);
            o1 = __builtin_amdgcn_mfma_f32_16x16x32_bf16(ap, bv1, o1, 0, 0, 0);
            pb ^= 1;
        }

        #pragma unroll
        for (int r = 0; r < 4; r++) {
            float l = lp[r];
            #pragma unroll
            for (int off = 1; off < 16; off <<= 1) l += __shfl_xor(l, off, 16);
            int q = q0 + quad * 4 + r;
            if (q < NQ) {
                float invl = 1.0f / l;
                __bf16* op = aout + ((long)(b * NQ + q) * CDIM + h * HD);
                op[n]      = (__bf16)(o0[r] * invl);
                op[16 + n] = (__bf16)(o1[r] * invl);
            }
        }
    }
}

// ============ msdeform bilinear sampling; vproj rows = (v*BS+b) ============
__global__ __launch_bounds__(256) void msds_kernel(
    const __bf16* __restrict__ vproj, const float* __restrict__ soaw,
    const float* __restrict__ refp, __bf16* __restrict__ out)
{
    int bq = blockIdx.x; int b = bq / NQ; int q = bq % NQ;
    int t = threadIdx.x; int h = t / HD; int d = t % HD;
    float rx = refp[(b * NQ + q) * 2 + 0];
    float ry = refp[(b * NQ + q) * 2 + 1];
    const float* rowp = soaw + (long)(b * NQ + q) * 96;
    const float* offp = rowp + h * 8;
    const float* awp  = rowp + 64 + h * 4;
    float a0 = awp[0], a1 = awp[1], a2 = awp[2], a3 = awp[3];
    float m = fmaxf(fmaxf(a0, a1), fmaxf(a2, a3));
    float e0 = __expf(a0 - m), e1 = __expf(a1 - m), e2 = __expf(a2 - m), e3 = __expf(a3 - m);
    float invs = 1.0f / (e0 + e1 + e2 + e3);
    float acc = 0.f;
    #pragma unroll
    for (int p = 0; p < PN; p++) {
        float ew = (p == 0 ? e0 : p == 1 ? e1 : p == 2 ? e2 : e3) * invs;
        float xim = rx * (float)WBEV + offp[p * 2 + 0] - 0.5f;
        float yim = ry * (float)HBEV + offp[p * 2 + 1] - 0.5f;
        float x0f = floorf(xim), y0f = floorf(yim);
        float lx = xim - x0f, ly = yim - y0f;
        int x0 = (int)x0f, y0 = (int)y0f;
        float gsum = 0.f;
        #pragma unroll
        for (int dy = 0; dy < 2; dy++) {
            #pragma unroll
            for (int dx = 0; dx < 2; dx++) {
                int xi = x0 + dx, yi = y0 + dy;
                float w = (dx ? lx : 1.f - lx) * (dy ? ly : 1.f - ly);
                bool ok = (xi >= 0 && xi < WBEV && yi >= 0 && yi < HBEV);
                int xc = min(max(xi, 0), WBEV - 1);
                int yc = min(max(yi, 0), HBEV - 1);
                int idx = yc * WBEV + xc;
                float gv = (float)vproj[((long)(idx * BS + b)) * CDIM + h * HD + d];
                gsum += (ok ? w : 0.f) * gv;
            }
        }
        acc += ew * gsum;
    }
    out[(b * NQ + q) * CDIM + h * HD + d] = (__bf16)acc;
}

extern "C" void kernel_launch(void* const* d_in, const int* in_sizes, int n_in,
                              void* d_out, int out_size, void* d_ws, size_t ws_size,
                              hipStream_t stream) {
    const float* query = (const float*)d_in[0];
    const float* value = (const float*)d_in[1];
    const float* qpos  = (const float*)d_in[2];
    const float* refp  = (const float*)d_in[3];
    const float* in_w  = (const float*)d_in[6];
    const float* in_b  = (const float*)d_in[7];
    const float* mha_ow = (const float*)d_in[8];
    const float* mha_ob = (const float*)d_in[9];
    const float* so_w  = (const float*)d_in[10];
    const float* so_b  = (const float*)d_in[11];
    const float* aw_w  = (const float*)d_in[12];
    const float* aw_b  = (const float*)d_in[13];
    const float* vp_w  = (const float*)d_in[14];
    const float* vp_b  = (const float*)d_in[15];
    const float* op_w  = (const float*)d_in[16];
    const float* op_b  = (const float*)d_in[17];
    const float* ffn_w1 = (const float*)d_in[18];
    const float* ffn_b1 = (const float*)d_in[19];
    const float* ffn_w2 = (const float*)d_in[20];
    const float* ffn_b2 = (const float*)d_in[21];
    const float* ln1_g = (const float*)d_in[22];
    const float* ln1_b = (const float*)d_in[23];
    const float* ln2_g = (const float*)d_in[24];
    const float* ln2_b = (const float*)d_in[25];
    const float* ln3_g = (const float*)d_in[26];
    const float* ln3_b = (const float*)d_in[27];
    float* out = (float*)d_out;

    const long NTOK = (long)BS * NQ * CDIM;   // 1,024,000

    float* x      = (float*)d_ws;
    float* qpos_t = x + NTOK;
    float* x1     = qpos_t + NTOK;
    float* x2     = x1 + NTOK;
    float* soaw   = x2 + NTOK;                       // 4000*96
    float* bsmall = soaw + (long)BS * NQ * 96;       // 128
    __bf16* x_bf   = (__bf16*)(bsmall + 128);
    __bf16* xq_bf  = x_bf + NTOK;
    __bf16* qk_bf  = xq_bf + NTOK;                   // 2*NTOK (q|k, stride 512)
    __bf16* vh_bf  = qk_bf + 2 * NTOK;
    __bf16* aA_bf  = vh_bf + NTOK;
    __bf16* x2_bf  = aA_bf + NTOK;
    __bf16* h1_bf  = x2_bf + NTOK;                   // 2*NTOK
    __bf16* vpj_bf = h1_bf + 2 * NTOK;               // 20,480,000
    __bf16* wb     = vpj_bf + (long)BS * NVAL * CDIM;
    __bf16* inw_b  = wb;
    __bf16* mow_b  = wb + 196608;
    __bf16* vpw_b  = wb + 262144;
    __bf16* opw_b  = wb + 327680;
    __bf16* fw1_b  = wb + 393216;
    __bf16* fw2_b  = wb + 524288;
    __bf16* wsmall = wb + 655360;                    // 128x256

    const int M = BS * NQ;
    dim3 blk(256);

    prep_all_kernel<<<4673, blk, 0, stream>>>(
        query, qpos, in_w, mha_ow, vp_w, op_w, ffn_w1, ffn_w2,
        so_w, aw_w, so_b, aw_b,
        x, qpos_t, x_bf, xq_bf, wb, wsmall, bsmall);

    // q|k|v fused in-proj (N=768, 756 blocks)
    qkv_kernel<<<dim3(12, 63), blk, 0, stream>>>(xq_bf, x_bf, inw_b, in_b, qk_bf, vh_bf);

    // flash attention (512 blocks, FIRST) + value projection (1250 blocks)
    fvg_kernel<<<1762, blk, 0, stream>>>(value, vpw_b, vp_b, vpj_bf,
                                         qk_bf, vh_bf, aA_bf);

    // mha out-proj + residual(x) + LN1 + (+qpos -> xq_bf)
    gemmln_kernel<256, 0><<<250, blk, 0, stream>>>(
        aA_bf, mow_b, mha_ob, x, ln1_g, ln1_b, qpos_t, x1, xq_bf);

    // sampling-offset + attn-weight projection (N=96, padded-128 weights)
    mgemm_kernel<32, 128><<<dim3(1, 125), blk, 0, stream>>>(
        xq_bf, wsmall, bsmall, soaw, nullptr, M, 96, 256, 0);

    msds_kernel<<<M, blk, 0, stream>>>(vpj_bf, soaw, refp, aA_bf);

    // op-proj + residual(x1) + LN2 -> x2 fp32 + bf16
    gemmln_kernel<256, 1><<<250, blk, 0, stream>>>(
        aA_bf, opw_b, op_b, x1, ln2_g, ln2_b, nullptr, x2, x2_bf);

    // FFN1 (relu)
    mgemm_kernel<64, 64><<<dim3(8, 63), blk, 0, stream>>>(
        x2_bf, fw1_b, ffn_b1, nullptr, h1_bf, M, 512, 256, 1);

    // FFN2 + residual(x2) + LN3 + transpose -> out
    gemmln_kernel<512, 2><<<250, blk, 0, stream>>>(
        h1_bf, fw2_b, ffn_b2, x2, ln3_g, ln3_b, nullptr, out, nullptr);
}

// Round 9
// 276.800 us; speedup vs baseline: 1.1334x; 1.1334x over previous
//
#include <hip/hip_runtime.h>
#include <hip/hip_bf16.h>
#include <cmath>

#define BS   4
#define NQ   1000
#define CDIM 256
#define NH   8
#define HD   32
#define NVAL 20000
#define FFND 512
#define PN   4
#define WBEV 100
#define HBEV 200
#define TK   32

typedef __bf16 v8bf __attribute__((ext_vector_type(8)));
typedef float  v4f  __attribute__((ext_vector_type(4)));

__device__ __forceinline__ void gload_lds16(const void* g, void* l) {
    __builtin_amdgcn_global_load_lds(
        (const __attribute__((address_space(1))) unsigned int*)g,
        (__attribute__((address_space(3))) unsigned int*)l, 16, 0, 0);
}

// ============ vgemm rider block: value-proj 128x128 tile, LDS-staged ========
// vb in [0,1250): bm=(vb>>1)*128 (row m = v*BS+b native order), bn=(vb&1)*128.
// Needs 32768 B of smem.
__device__ __forceinline__ void vgemm_block(
    int vb, const float* __restrict__ value, const __bf16* __restrict__ Wv,
    const float* __restrict__ bv, __bf16* __restrict__ vpj, char* smem)
{
    __bf16* As = (__bf16*)smem;             // [128][64]
    __bf16* Bs = (__bf16*)(smem + 16384);   // [128][64]
    int tid = threadIdx.x;
    int wave = tid >> 6, lane = tid & 63, quad = lane >> 4, n16 = lane & 15;
    int bm = (vb >> 1) * 128, bn = (vb & 1) * 128;
    int wm = (wave & 1) * 64, wn = (wave >> 1) * 64;
    v4f acc[4][4] = {};

    for (int k0 = 0; k0 < 256; k0 += 64) {
        float4 fa[4][2];
        #pragma unroll
        for (int i = 0; i < 4; i++) {
            int e = i * 256 + tid;
            int r = e >> 3, c = (e & 7) ^ (r & 7);
            const float* p = value + (long)(bm + r) * 256 + k0 + c * 8;
            fa[i][0] = *(const float4*)p;
            fa[i][1] = *(const float4*)(p + 4);
        }
        __syncthreads();
        #pragma unroll
        for (int i = 0; i < 4; i++) {
            int e = i * 256 + tid;
            v8bf v;
            v[0] = (__bf16)fa[i][0].x; v[1] = (__bf16)fa[i][0].y;
            v[2] = (__bf16)fa[i][0].z; v[3] = (__bf16)fa[i][0].w;
            v[4] = (__bf16)fa[i][1].x; v[5] = (__bf16)fa[i][1].y;
            v[6] = (__bf16)fa[i][1].z; v[7] = (__bf16)fa[i][1].w;
            *(v8bf*)(As + e * 8) = v;
        }
        #pragma unroll
        for (int i = 0; i < 4; i++) {
            int e = i * 256 + tid;
            int r = e >> 3, c = (e & 7) ^ (r & 7);
            gload_lds16(Wv + (long)(bn + r) * 256 + k0 + c * 8, Bs + e * 8);
        }
        __syncthreads();
        #pragma unroll
        for (int s = 0; s < 2; s++) {
            v8bf af[4], bfr[4];
            #pragma unroll
            for (int mi = 0; mi < 4; mi++) {
                int row = wm + mi * 16 + n16;
                af[mi] = *(v8bf*)&As[row * 64 + (((quad + s * 4) ^ (row & 7))) * 8];
            }
            #pragma unroll
            for (int nj = 0; nj < 4; nj++) {
                int row = wn + nj * 16 + n16;
                bfr[nj] = *(v8bf*)&Bs[row * 64 + (((quad + s * 4) ^ (row & 7))) * 8];
            }
            #pragma unroll
            for (int mi = 0; mi < 4; mi++)
                #pragma unroll
                for (int nj = 0; nj < 4; nj++)
                    acc[mi][nj] = __builtin_amdgcn_mfma_f32_16x16x32_bf16(af[mi], bfr[nj], acc[mi][nj], 0, 0, 0);
        }
    }
    #pragma unroll
    for (int mi = 0; mi < 4; mi++) {
        #pragma unroll
        for (int r = 0; r < 4; r++) {
            int m = bm + wm + mi * 16 + quad * 4 + r;
            #pragma unroll
            for (int nj = 0; nj < 4; nj++) {
                int nn = bn + wn + nj * 16 + n16;
                vpj[(long)m * 256 + nn] = (__bf16)(acc[mi][nj][r] + bv[nn]);
            }
        }
    }
}

// ============ prep_all: weight cast | prep | soaw pack ============
__global__ __launch_bounds__(256) void prep_all_kernel(
    const float* __restrict__ query, const float* __restrict__ qpos,
    const float* __restrict__ in_w, const float* __restrict__ mha_ow,
    const float* __restrict__ vp_w, const float* __restrict__ op_w,
    const float* __restrict__ ffn_w1, const float* __restrict__ ffn_w2,
    const float* __restrict__ so_w, const float* __restrict__ aw_w,
    const float* __restrict__ so_b, const float* __restrict__ aw_b,
    float* __restrict__ x, float* __restrict__ qpos_t,
    __bf16* __restrict__ x_bf, __bf16* __restrict__ xq_bf,
    __bf16* __restrict__ wb, __bf16* __restrict__ wsmall,
    float* __restrict__ bsmall)
{
    int blk = blockIdx.x, tid = threadIdx.x;
    if (blk < 640) {
        long e = ((long)blk * 256 + tid) * 4;
        const float* src; long off;
        if      (e < 196608) { src = in_w;   off = e; }
        else if (e < 262144) { src = mha_ow; off = e - 196608; }
        else if (e < 327680) { src = vp_w;   off = e - 262144; }
        else if (e < 393216) { src = op_w;   off = e - 327680; }
        else if (e < 524288) { src = ffn_w1; off = e - 393216; }
        else                 { src = ffn_w2; off = e - 524288; }
        float4 v = *(const float4*)(src + off);
        __bf16* d = wb + e;
        d[0] = (__bf16)v.x; d[1] = (__bf16)v.y; d[2] = (__bf16)v.z; d[3] = (__bf16)v.w;
    } else if (blk < 4640) {
        int qb = blk - 640;
        int q = qb / BS, b = qb % BS;
        float qv = query[(q * BS + b) * CDIM + tid];
        float pv = qpos [(q * BS + b) * CDIM + tid];
        int o = (b * NQ + q) * CDIM + tid;
        x[o] = qv; qpos_t[o] = pv;
        x_bf[o] = (__bf16)qv; xq_bf[o] = (__bf16)(qv + pv);
    } else if (blk < 4672) {
        long e = ((long)(blk - 4640) * 256 + tid) * 4;
        int row = (int)(e >> 8), col = (int)(e & 255);
        float4 v = {0.f, 0.f, 0.f, 0.f};
        if (row < 64)      v = *(const float4*)(so_w + row * 256 + col);
        else if (row < 96) v = *(const float4*)(aw_w + (row - 64) * 256 + col);
        __bf16* d = wsmall + e;
        d[0] = (__bf16)v.x; d[1] = (__bf16)v.y; d[2] = (__bf16)v.z; d[3] = (__bf16)v.w;
    } else {
        if (tid < 128) bsmall[tid] = tid < 64 ? so_b[tid] : (tid < 96 ? aw_b[tid - 64] : 0.f);
    }
}

// ============ MFMA bf16 GEMM, BK=64, 1-D grid, optional vgemm rider ========
template<int TBM, int TBN, bool RIDE>
__global__ __launch_bounds__(256) void mgemm_kernel(
    const __bf16* __restrict__ A, const __bf16* __restrict__ W,
    const float* __restrict__ bias, float* __restrict__ Yf,
    __bf16* __restrict__ Yb, int M, int N, int K, int relu, int nx, int nprim,
    const float* __restrict__ value, const __bf16* __restrict__ Wv,
    const float* __restrict__ bv, __bf16* __restrict__ vpj, int voff)
{
    constexpr int PRIM = TBM * 64 * 2 + TBN * 64 * 2;
    constexpr int SZ = RIDE ? (PRIM > 32768 ? PRIM : 32768) : PRIM;
    __shared__ __align__(16) char smem[SZ];
    if (RIDE && (int)blockIdx.x >= nprim) {
        vgemm_block(blockIdx.x - nprim + voff, value, Wv, bv, vpj, smem);
        return;
    }
    constexpr int WMF = TBM / 32;
    constexpr int WNF = TBN / 32;
    __bf16* As = (__bf16*)smem;                 // [TBM][64]
    __bf16* Bs = (__bf16*)(smem + TBM * 128);   // [TBN][64]
    int bm = (blockIdx.x / nx) * TBM, bn = (blockIdx.x % nx) * TBN;
    int tid = threadIdx.x;
    int wave = tid >> 6, lane = tid & 63, quad = lane >> 4, n16 = lane & 15;
    int wm = (wave & 1) * (TBM / 2), wn = (wave >> 1) * (TBN / 2);
    v4f acc[WMF][WNF] = {};

    for (int k0 = 0; k0 < K; k0 += 64) {
        __syncthreads();
        #pragma unroll
        for (int i = 0; i < TBM * 8 / 256; i++) {
            int e = i * 256 + tid;
            int r = e >> 3, c = (e & 7) ^ (r & 7);
            int row = bm + r; if (row > M - 1) row = M - 1;
            gload_lds16(A + (long)row * K + k0 + c * 8, As + e * 8);
        }
        #pragma unroll
        for (int i = 0; i < TBN * 8 / 256; i++) {
            int e = i * 256 + tid;
            int r = e >> 3, c = (e & 7) ^ (r & 7);
            gload_lds16(W + (long)(bn + r) * K + k0 + c * 8, Bs + e * 8);
        }
        __syncthreads();
        #pragma unroll
        for (int s = 0; s < 2; s++) {
            v8bf af[WMF], bfr[WNF];
            #pragma unroll
            for (int mi = 0; mi < WMF; mi++) {
                int row = wm + mi * 16 + n16;
                af[mi] = *(v8bf*)&As[row * 64 + (((quad + s * 4) ^ (row & 7))) * 8];
            }
            #pragma unroll
            for (int nj = 0; nj < WNF; nj++) {
                int row = wn + nj * 16 + n16;
                bfr[nj] = *(v8bf*)&Bs[row * 64 + (((quad + s * 4) ^ (row & 7))) * 8];
            }
            #pragma unroll
            for (int mi = 0; mi < WMF; mi++)
                #pragma unroll
                for (int nj = 0; nj < WNF; nj++)
                    acc[mi][nj] = __builtin_amdgcn_mfma_f32_16x16x32_bf16(af[mi], bfr[nj], acc[mi][nj], 0, 0, 0);
        }
    }

    #pragma unroll
    for (int mi = 0; mi < WMF; mi++) {
        #pragma unroll
        for (int r = 0; r < 4; r++) {
            int m = bm + wm + mi * 16 + quad * 4 + r;
            if (m >= M) continue;
            #pragma unroll
            for (int nj = 0; nj < WNF; nj++) {
                int nn = bn + wn + nj * 16 + n16;
                if (nn >= N) continue;
                float v = acc[mi][nj][r] + bias[nn];
                if (relu) v = fmaxf(v, 0.f);
                if (Yf) Yf[(long)m * N + nn] = v;
                if (Yb) Yb[(long)m * N + nn] = (__bf16)v;
            }
        }
    }
}

// ============ fused q|k|v projection (756 blocks) + vgemm rider ============
__global__ __launch_bounds__(256) void qkvv_kernel(
    const __bf16* __restrict__ xq, const __bf16* __restrict__ xv,
    const __bf16* __restrict__ W, const float* __restrict__ bias,
    __bf16* __restrict__ qk, __bf16* __restrict__ vh,
    const float* __restrict__ value, const __bf16* __restrict__ Wv,
    const float* __restrict__ bv, __bf16* __restrict__ vpj, int voff)
{
    __shared__ __align__(16) char smem[32768];
    int tid = threadIdx.x;
    if (blockIdx.x >= 756) {
        vgemm_block(blockIdx.x - 756 + voff, value, Wv, bv, vpj, smem);
        return;
    }
    int blk = blockIdx.x;
    int bn = (blk % 12) * 64, bm = (blk / 12) * 64;
    __bf16* As = (__bf16*)smem;             // [64][64]
    __bf16* Bs = (__bf16*)(smem + 8192);    // [64][64]
    const __bf16* A = (bn < 512) ? xq : xv;
    int wave = tid >> 6, lane = tid & 63, quad = lane >> 4, n16 = lane & 15;
    int wm = (wave & 1) * 32, wn = (wave >> 1) * 32;
    v4f acc[2][2] = {};

    for (int k0 = 0; k0 < 256; k0 += 64) {
        __syncthreads();
        #pragma unroll
        for (int i = 0; i < 2; i++) {
            int e = i * 256 + tid;
            int r = e >> 3, c = (e & 7) ^ (r & 7);
            int row = bm + r; if (row > BS * NQ - 1) row = BS * NQ - 1;
            gload_lds16(A + (long)row * 256 + k0 + c * 8, As + e * 8);
        }
        #pragma unroll
        for (int i = 0; i < 2; i++) {
            int e = i * 256 + tid;
            int r = e >> 3, c = (e & 7) ^ (r & 7);
            gload_lds16(W + (long)(bn + r) * 256 + k0 + c * 8, Bs + e * 8);
        }
        __syncthreads();
        #pragma unroll
        for (int s = 0; s < 2; s++) {
            v8bf af[2], bfr[2];
            #pragma unroll
            for (int mi = 0; mi < 2; mi++) {
                int row = wm + mi * 16 + n16;
                af[mi] = *(v8bf*)&As[row * 64 + (((quad + s * 4) ^ (row & 7))) * 8];
            }
            #pragma unroll
            for (int nj = 0; nj < 2; nj++) {
                int row = wn + nj * 16 + n16;
                bfr[nj] = *(v8bf*)&Bs[row * 64 + (((quad + s * 4) ^ (row & 7))) * 8];
            }
            #pragma unroll
            for (int mi = 0; mi < 2; mi++)
                #pragma unroll
                for (int nj = 0; nj < 2; nj++)
                    acc[mi][nj] = __builtin_amdgcn_mfma_f32_16x16x32_bf16(af[mi], bfr[nj], acc[mi][nj], 0, 0, 0);
        }
    }

    #pragma unroll
    for (int mi = 0; mi < 2; mi++) {
        #pragma unroll
        for (int r = 0; r < 4; r++) {
            int m = bm + wm + mi * 16 + quad * 4 + r;
            if (m >= BS * NQ) continue;
            #pragma unroll
            for (int nj = 0; nj < 2; nj++) {
                int nn = bn + wn + nj * 16 + n16;
                float v = acc[mi][nj][r] + bias[nn];
                if (nn < 512) qk[(long)m * 512 + nn] = (__bf16)v;
                else          vh[(long)m * 256 + (nn - 512)] = (__bf16)v;
            }
        }
    }
}

// ============ flash attention (512 blocks) + vgemm rider ============
__global__ __launch_bounds__(256) void fattnv_kernel(
    const __bf16* __restrict__ qk, const __bf16* __restrict__ vh,
    __bf16* __restrict__ aout,
    const float* __restrict__ value, const __bf16* __restrict__ Wv,
    const float* __restrict__ bv, __bf16* __restrict__ vpj, int voff)
{
    __shared__ __align__(16) char smem[32768];
    int tid = threadIdx.x;
    if (blockIdx.x >= 512) {
        vgemm_block(blockIdx.x - 512 + voff, value, Wv, bv, vpj, smem);
        return;
    }
    int fb = blockIdx.x;
    int qt = fb & 15, h = (fb >> 4) & 7, b = fb >> 7;
    __bf16* Ks = (__bf16*)smem;             // [2][TK][40]
    __bf16* Vt = (__bf16*)(smem + 5120);    // [2][HD][40]
    __bf16* Pl = (__bf16*)(smem + 10240);   // [4][16][40]
    int wave = tid >> 6, lane = tid & 63, quad = lane >> 4, n = lane & 15;
    int q0 = qt * 64 + wave * 16;
    const float scale = 0.17677669529663687f;
    const float M0 = 8.0f;

    int qrow = q0 + n; if (qrow > NQ - 1) qrow = NQ - 1;
    v8bf aq = *(const v8bf*)(qk + (long)(b * NQ + qrow) * 512 + h * HD + quad * 8);

    v4f o0 = {}, o1 = {};
    float lp[4] = {0.f, 0.f, 0.f, 0.f};

    int sv = tid >> 7;
    int t2 = tid & 127;
    int key = t2 >> 2;
    int d8 = (t2 & 3) * 8;
    int vcol = key ^ (((d8 >> 3) & 1) << 4);

    auto loadtile = [&](int k0) -> v8bf {
        int krow = k0 + key; if (krow > NQ - 1) krow = NQ - 1;
        const __bf16* p = sv ? (vh + (long)(b * NQ + krow) * CDIM + h * HD + d8)
                             : (qk + (long)(b * NQ + krow) * 512 + 256 + h * HD + d8);
        return *(const v8bf*)p;
    };

    v8bf stg = loadtile(0);
    int pb = 0;
    for (int k0 = 0; k0 < NQ; k0 += TK) {
        if (sv == 0) {
            *(v8bf*)&Ks[(pb * TK + key) * 40 + d8] = stg;
        } else {
            #pragma unroll
            for (int j = 0; j < 8; j++) Vt[(pb * HD + d8 + j) * 40 + vcol] = stg[j];
        }
        if (k0 + TK < NQ) stg = loadtile(k0 + TK);
        __syncthreads();

        v8bf bk0 = *(v8bf*)&Ks[(pb * TK + n) * 40 + quad * 8];
        v8bf bk1 = *(v8bf*)&Ks[(pb * TK + 16 + n) * 40 + quad * 8];
        v4f z = {};
        v4f S0 = __builtin_amdgcn_mfma_f32_16x16x32_bf16(aq, bk0, z, 0, 0, 0);
        v4f S1 = __builtin_amdgcn_mfma_f32_16x16x32_bf16(aq, bk1, z, 0, 0, 0);

        bool last = (k0 + TK > NQ);
        float p0[4], p1[4];
        #pragma unroll
        for (int r = 0; r < 4; r++) {
            p0[r] = __expf(fmaf(S0[r], scale, -M0));
            p1[r] = __expf(fmaf(S1[r], scale, -M0));
            if (last) {
                if (k0 + n >= NQ)      p0[r] = 0.f;
                if (k0 + 16 + n >= NQ) p1[r] = 0.f;
            }
            lp[r] += p0[r] + p1[r];
        }
        #pragma unroll
        for (int r = 0; r < 4; r++) {
            Pl[(wave * 16 + quad * 4 + r) * 40 + n]      = (__bf16)p0[r];
            Pl[(wave * 16 + quad * 4 + r) * 40 + 16 + n] = (__bf16)p1[r];
        }
        asm volatile("s_waitcnt lgkmcnt(0)" ::: "memory");
        v8bf ap = *(v8bf*)&Pl[(wave * 16 + n) * 40 + quad * 8];
        int vc = (quad * 8) ^ (((n >> 3) & 1) << 4);
        v8bf bv0 = *(v8bf*)&Vt[(pb * HD + n) * 40 + vc];
        v8bf bv1 = *(v8bf*)&Vt[(pb * HD + 16 + n) * 40 + vc];
        o0 = __builtin_amdgcn_mfma_f32_16x16x32_bf16(ap, bv0, o0, 0, 0, 0);
        o1 = __builtin_amdgcn_mfma_f32_16x16x32_bf16(ap, bv1, o1, 0, 0, 0);
        pb ^= 1;
    }

    #pragma unroll
    for (int r = 0; r < 4; r++) {
        float l = lp[r];
        #pragma unroll
        for (int off = 1; off < 16; off <<= 1) l += __shfl_xor(l, off, 16);
        int q = q0 + quad * 4 + r;
        if (q < NQ) {
            float invl = 1.0f / l;
            __bf16* op = aout + ((long)(b * NQ + q) * CDIM + h * HD);
            op[n]      = (__bf16)(o0[r] * invl);
            op[16 + n] = (__bf16)(o1[r] * invl);
        }
    }
}

// ============ GEMM + residual + LayerNorm epilogue, optional rider ==========
template<int KD, int MODE, bool RIDE>
__global__ __launch_bounds__(256) void gemmln_kernel(
    const __bf16* __restrict__ A, const __bf16* __restrict__ W,
    const float* __restrict__ bias, const float* __restrict__ res,
    const float* __restrict__ g, const float* __restrict__ beta,
    const float* __restrict__ qpos_t,
    float* __restrict__ outf, __bf16* __restrict__ outb,
    const float* __restrict__ value, const __bf16* __restrict__ Wv,
    const float* __restrict__ bv, __bf16* __restrict__ vpj, int voff)
{
    __shared__ __align__(16) char smem[35328];
    int tid = threadIdx.x;
    if (RIDE && blockIdx.x >= 250) {
        vgemm_block(blockIdx.x - 250 + voff, value, Wv, bv, vpj, smem);
        return;
    }
    __bf16* As = (__bf16*)smem;             // [16][64]
    __bf16* Bs = (__bf16*)(smem + 2048);    // [256][64]
    float* redS = (float*)(smem + 34816);   // [4][16]
    float* redQ = redS + 64;                // [4][16]
    int bm = blockIdx.x * 16;
    int wave = tid >> 6, lane = tid & 63, quad = lane >> 4, n16 = lane & 15;
    int wn = wave * 64;
    v4f acc[4] = {};

    for (int k0 = 0; k0 < KD; k0 += 64) {
        __syncthreads();
        if (tid < 128) {
            int e = tid;
            int r = e >> 3, c = (e & 7) ^ (r & 7);
            gload_lds16(A + (long)(bm + r) * KD + k0 + c * 8, As + e * 8);
        }
        #pragma unroll
        for (int i = 0; i < 8; i++) {
            int e = i * 256 + tid;
            int r = e >> 3, c = (e & 7) ^ (r & 7);
            gload_lds16(W + (long)r * KD + k0 + c * 8, Bs + e * 8);
        }
        __syncthreads();
        #pragma unroll
        for (int s = 0; s < 2; s++) {
            v8bf af = *(v8bf*)&As[n16 * 64 + (((quad + s * 4) ^ (n16 & 7))) * 8];
            #pragma unroll
            for (int nj = 0; nj < 4; nj++) {
                int row = wn + nj * 16 + n16;
                v8bf bfr = *(v8bf*)&Bs[row * 64 + (((quad + s * 4) ^ (row & 7))) * 8];
                acc[nj] = __builtin_amdgcn_mfma_f32_16x16x32_bf16(af, bfr, acc[nj], 0, 0, 0);
            }
        }
    }

    float y[4][4], s1[4] = {}, s2[4] = {};
    #pragma unroll
    for (int r = 0; r < 4; r++) {
        int m = bm + quad * 4 + r;
        #pragma unroll
        for (int nj = 0; nj < 4; nj++) {
            int nn = wn + nj * 16 + n16;
            float v = acc[nj][r] + bias[nn] + res[(long)m * 256 + nn];
            y[r][nj] = v;
            s1[r] += v; s2[r] += v * v;
        }
    }
    #pragma unroll
    for (int r = 0; r < 4; r++) {
        #pragma unroll
        for (int off = 1; off < 16; off <<= 1) {
            s1[r] += __shfl_xor(s1[r], off, 16);
            s2[r] += __shfl_xor(s2[r], off, 16);
        }
    }
    if (n16 == 0) {
        #pragma unroll
        for (int r = 0; r < 4; r++) {
            redS[wave * 16 + quad * 4 + r] = s1[r];
            redQ[wave * 16 + quad * 4 + r] = s2[r];
        }
    }
    __syncthreads();
    #pragma unroll
    for (int r = 0; r < 4; r++) {
        int mr = quad * 4 + r;
        float ts = redS[mr] + redS[16 + mr] + redS[32 + mr] + redS[48 + mr];
        float tq = redQ[mr] + redQ[16 + mr] + redQ[32 + mr] + redQ[48 + mr];
        float mean = ts * (1.0f / 256.0f);
        float var = tq * (1.0f / 256.0f) - mean * mean;
        float rinv = rsqrtf(var + 1e-5f);
        int m = bm + mr;
        #pragma unroll
        for (int nj = 0; nj < 4; nj++) {
            int nn = wn + nj * 16 + n16;
            float o = (y[r][nj] - mean) * rinv * g[nn] + beta[nn];
            if (MODE == 0) {
                outf[(long)m * 256 + nn] = o;
                outb[(long)m * 256 + nn] = (__bf16)(o + qpos_t[(long)m * 256 + nn]);
            } else if (MODE == 1) {
                outf[(long)m * 256 + nn] = o;
                outb[(long)m * 256 + nn] = (__bf16)o;
            } else {
                int b = m / NQ, q = m % NQ;
                outf[(long)(q * BS + b) * 256 + nn] = o;
            }
        }
    }
}

// ============ msdeform bilinear sampling; vproj rows = (v*BS+b) ============
__global__ __launch_bounds__(256) void msds_kernel(
    const __bf16* __restrict__ vproj, const float* __restrict__ soaw,
    const float* __restrict__ refp, __bf16* __restrict__ out)
{
    int bq = blockIdx.x; int b = bq / NQ; int q = bq % NQ;
    int t = threadIdx.x; int h = t / HD; int d = t % HD;
    float rx = refp[(b * NQ + q) * 2 + 0];
    float ry = refp[(b * NQ + q) * 2 + 1];
    const float* rowp = soaw + (long)(b * NQ + q) * 96;
    const float* offp = rowp + h * 8;
    const float* awp  = rowp + 64 + h * 4;
    float a0 = awp[0], a1 = awp[1], a2 = awp[2], a3 = awp[3];
    float m = fmaxf(fmaxf(a0, a1), fmaxf(a2, a3));
    float e0 = __expf(a0 - m), e1 = __expf(a1 - m), e2 = __expf(a2 - m), e3 = __expf(a3 - m);
    float invs = 1.0f / (e0 + e1 + e2 + e3);
    float acc = 0.f;
    #pragma unroll
    for (int p = 0; p < PN; p++) {
        float ew = (p == 0 ? e0 : p == 1 ? e1 : p == 2 ? e2 : e3) * invs;
        float xim = rx * (float)WBEV + offp[p * 2 + 0] - 0.5f;
        float yim = ry * (float)HBEV + offp[p * 2 + 1] - 0.5f;
        float x0f = floorf(xim), y0f = floorf(yim);
        float lx = xim - x0f, ly = yim - y0f;
        int x0 = (int)x0f, y0 = (int)y0f;
        float gsum = 0.f;
        #pragma unroll
        for (int dy = 0; dy < 2; dy++) {
            #pragma unroll
            for (int dx = 0; dx < 2; dx++) {
                int xi = x0 + dx, yi = y0 + dy;
                float w = (dx ? lx : 1.f - lx) * (dy ? ly : 1.f - ly);
                bool ok = (xi >= 0 && xi < WBEV && yi >= 0 && yi < HBEV);
                int xc = min(max(xi, 0), WBEV - 1);
                int yc = min(max(yi, 0), HBEV - 1);
                int idx = yc * WBEV + xc;
                float gv = (float)vproj[((long)(idx * BS + b)) * CDIM + h * HD + d];
                gsum += (ok ? w : 0.f) * gv;
            }
        }
        acc += ew * gsum;
    }
    out[(b * NQ + q) * CDIM + h * HD + d] = (__bf16)acc;
}

extern "C" void kernel_launch(void* const* d_in, const int* in_sizes, int n_in,
                              void* d_out, int out_size, void* d_ws, size_t ws_size,
                              hipStream_t stream) {
    const float* query = (const float*)d_in[0];
    const float* value = (const float*)d_in[1];
    const float* qpos  = (const float*)d_in[2];
    const float* refp  = (const float*)d_in[3];
    const float* in_w  = (const float*)d_in[6];
    const float* in_b  = (const float*)d_in[7];
    const float* mha_ow = (const float*)d_in[8];
    const float* mha_ob = (const float*)d_in[9];
    const float* so_w  = (const float*)d_in[10];
    const float* so_b  = (const float*)d_in[11];
    const float* aw_w  = (const float*)d_in[12];
    const float* aw_b  = (const float*)d_in[13];
    const float* vp_w  = (const float*)d_in[14];
    const float* vp_b  = (const float*)d_in[15];
    const float* op_w  = (const float*)d_in[16];
    const float* op_b  = (const float*)d_in[17];
    const float* ffn_w1 = (const float*)d_in[18];
    const float* ffn_b1 = (const float*)d_in[19];
    const float* ffn_w2 = (const float*)d_in[20];
    const float* ffn_b2 = (const float*)d_in[21];
    const float* ln1_g = (const float*)d_in[22];
    const float* ln1_b = (const float*)d_in[23];
    const float* ln2_g = (const float*)d_in[24];
    const float* ln2_b = (const float*)d_in[25];
    const float* ln3_g = (const float*)d_in[26];
    const float* ln3_b = (const float*)d_in[27];
    float* out = (float*)d_out;

    const long NTOK = (long)BS * NQ * CDIM;   // 1,024,000

    float* x      = (float*)d_ws;
    float* qpos_t = x + NTOK;
    float* x1     = qpos_t + NTOK;
    float* x2     = x1 + NTOK;
    float* soaw   = x2 + NTOK;                       // 4000*96
    float* bsmall = soaw + (long)BS * NQ * 96;       // 128
    __bf16* x_bf   = (__bf16*)(bsmall + 128);
    __bf16* xq_bf  = x_bf + NTOK;
    __bf16* qk_bf  = xq_bf + NTOK;                   // 2*NTOK (q|k, stride 512)
    __bf16* vh_bf  = qk_bf + 2 * NTOK;
    __bf16* aA_bf  = vh_bf + NTOK;
    __bf16* x2_bf  = aA_bf + NTOK;
    __bf16* h1_bf  = x2_bf + NTOK;                   // 2*NTOK
    __bf16* vpj_bf = h1_bf + 2 * NTOK;               // 20,480,000
    __bf16* wb     = vpj_bf + (long)BS * NVAL * CDIM;
    __bf16* inw_b  = wb;
    __bf16* mow_b  = wb + 196608;
    __bf16* vpw_b  = wb + 262144;
    __bf16* opw_b  = wb + 327680;
    __bf16* fw1_b  = wb + 393216;
    __bf16* fw2_b  = wb + 524288;
    __bf16* wsmall = wb + 655360;                    // 128x256

    dim3 blk(256);

    prep_all_kernel<<<4673, blk, 0, stream>>>(
        query, qpos, in_w, mha_ow, vp_w, op_w, ffn_w1, ffn_w2,
        so_w, aw_w, so_b, aw_b,
        x, qpos_t, x_bf, xq_bf, wb, wsmall, bsmall);

    // q|k|v in-proj (756 blocks) + vgemm chunk 0 (313)
    qkvv_kernel<<<1069, blk, 0, stream>>>(xq_bf, x_bf, inw_b, in_b, qk_bf, vh_bf,
                                          value, vpw_b, vp_b, vpj_bf, 0);

    // flash attention (512 blocks) + vgemm chunk 1 (313)
    fattnv_kernel<<<825, blk, 0, stream>>>(qk_bf, vh_bf, aA_bf,
                                           value, vpw_b, vp_b, vpj_bf, 313);

    // mha out-proj + residual(x) + LN1 (+qpos -> xq_bf)  (250) + chunk 2 (313)
    gemmln_kernel<256, 0, true><<<563, blk, 0, stream>>>(
        aA_bf, mow_b, mha_ob, x, ln1_g, ln1_b, qpos_t, x1, xq_bf,
        value, vpw_b, vp_b, vpj_bf, 626);

    // soaw projection (125 blocks) + vgemm chunk 3 (311)
    mgemm_kernel<32, 128, true><<<436, blk, 0, stream>>>(
        xq_bf, wsmall, bsmall, soaw, nullptr, BS * NQ, 96, 256, 0, 1, 125,
        value, vpw_b, vp_b, vpj_bf, 939);

    msds_kernel<<<BS * NQ, blk, 0, stream>>>(vpj_bf, soaw, refp, aA_bf);

    // op-proj + residual(x1) + LN2 -> x2 fp32 + bf16
    gemmln_kernel<256, 1, false><<<250, blk, 0, stream>>>(
        aA_bf, opw_b, op_b, x1, ln2_g, ln2_b, nullptr, x2, x2_bf,
        nullptr, nullptr, nullptr, nullptr, 0);

    // FFN1 (relu)
    mgemm_kernel<64, 64, false><<<504, blk, 0, stream>>>(
        x2_bf, fw1_b, ffn_b1, nullptr, h1_bf, BS * NQ, 512, 256, 1, 8, 504,
        nullptr, nullptr, nullptr, nullptr, 0);

    // FFN2 + residual(x2) + LN3 + transpose -> out
    gemmln_kernel<512, 2, false><<<250, blk, 0, stream>>>(
        h1_bf, fw2_b, ffn_b2, x2, ln3_g, ln3_b, nullptr, out, nullptr,
        nullptr, nullptr, nullptr, nullptr, 0);
}